// Round 6
// baseline (799.347 us; speedup 1.0000x reference)
//
#include <hip/hip_runtime.h>

// GroupedEmbeddingBag: T=8 tables [V=100000, D=128] fp32, B=4096 bags/table.
// out[b, t*D+d] = sum_{i in [offs[t][b], offs[t][b+1])} tables[t][values[t][i]][d] * psw[t][i]
//
// R7: per-table phased prestream+gather, STREAM-ORDER as the grid barrier.
//  - R6's cooperative launch was silently dropped by graph capture (output
//    stayed zero). Same mechanism, capture-safe vehicle: 16 back-to-back
//    launches on one stream; stream serialization = the barrier.
//  - Also fixes R6's footprint bug: 410 MB total > 256 MB L3; per-table
//    phases keep the active set at 51.2 MB (always L3-resident).
//  - prestream(t): 1024 blocks x 50 KB contiguous slices = table t streamed
//    exactly once at full DRAM efficiency (~8 us).
//  - gather(t): verified R3 loop (one wave/bag, 512B row per wave-load with
//    SGPR base, 16 rows in flight), 4096 bags of table t, warm L3.
//  Predict: total ~250-420 us if cold-random-HBM theory right; flat 565 with
//  fast gather dispatches -> external floor; slow warm gathers -> L3-random
//  wall. Either latter case => roofline.

namespace {
constexpr int T = 8;
constexpr int V = 100000;
constexpr int D = 128;
constexpr int B = 4096;
constexpr int N = 204800;
constexpr int PRE_BLOCKS = 1024;
constexpr int F4_PER_TABLE = V * D / 4;                    // 3,200,000
constexpr int F4_PER_BLOCK = F4_PER_TABLE / PRE_BLOCKS;    // 3125 (50 KB)
}

__device__ __forceinline__ float readlane_f(float v, int l) {
    return __int_as_float(__builtin_amdgcn_readlane(__float_as_int(v), l));
}

// ---- Kernel A: sequential prestream of one table into L3. --------------
__global__ __launch_bounds__(256) void prestream_kernel(
    const float* __restrict__ tab)      // tables + t*V*D
{
    const float4* __restrict__ tp = (const float4*)tab;
    const size_t base0 = (size_t)blockIdx.x * F4_PER_BLOCK;
    float keep = 0.f;
    for (int k = (int)threadIdx.x; k < F4_PER_BLOCK; k += 256) {
        const float4 v4 = tp[base0 + k];
        keep += v4.x + v4.y + v4.z + v4.w;   // force the loads
    }
    asm volatile("" :: "v"(keep));           // keep-alive, no DCE
}

// ---- Kernel B: gather one table's 4096 bags (R3 verified body). --------
__global__ __launch_bounds__(256) void gather_kernel(
    const float* __restrict__ tables,   // [T, V, D]
    const int* __restrict__ values,     // [T, N]
    const int* __restrict__ offsets,    // [T, B+1]
    const float* __restrict__ psw,      // [T, N]
    float* __restrict__ out,            // [B, T*D]
    int t)
{
    const int wave = threadIdx.x >> 6;            // 0..3
    const int lane = threadIdx.x & 63;
    const int b    = (blockIdx.x << 2) + wave;    // 0..4095

    int start = offsets[t * (B + 1) + b];
    int end   = offsets[t * (B + 1) + b + 1];
    start = __builtin_amdgcn_readfirstlane(start);
    end   = __builtin_amdgcn_readfirstlane(end);
    const int len = end - start;

    const float* __restrict__ tab  = tables + (size_t)t * (V * D);
    const int*   __restrict__ vals = values + (size_t)t * N + start;
    const float* __restrict__ wgt  = psw    + (size_t)t * N + start;

    float2 acc = make_float2(0.f, 0.f);

    for (int base = 0; base < len; base += 64) {
        const int rem = len - base;
        const int m   = rem < 64 ? rem : 64;      // rows in this chunk (1..64)

        const int pos  = base + lane;
        const int posc = pos < len ? pos : (len - 1);   // clamp: stay in-bag
        const int   vidx = vals[posc];
        const float vw   = (pos < len) ? wgt[posc] : 0.f;  // pad rows weigh 0

        const int ngrp = (m + 7) >> 3;            // 8-row groups, <= 8

        float2 bufA[8], bufB[8];                  // static-indexed only

        auto LOAD = [&](float2 (&buf)[8], int g) {
#pragma unroll
            for (int j = 0; j < 8; ++j) {
                const int r   = (g << 3) + j;                    // uniform
                const int row = __builtin_amdgcn_readlane(vidx, r); // SGPR idx
                buf[j] = *(const float2*)(tab + (size_t)row * D + lane * 2);
            }
        };
        auto FMA = [&](float2 (&buf)[8], int g) {
#pragma unroll
            for (int j = 0; j < 8; ++j) {
                const int r = (g << 3) + j;
                const float w = readlane_f(vw, r);               // SGPR weight
                acc.x = fmaf(buf[j].x, w, acc.x);
                acc.y = fmaf(buf[j].y, w, acc.y);
            }
        };

        LOAD(bufA, 0);
        int g = 0;
        for (; g + 2 <= ngrp; g += 2) {
            LOAD(bufB, g + 1);      // issue next 8 rows BEFORE waiting on A
            FMA(bufA, g);           // vmcnt(8): only A's rows drained
            if (g + 2 < ngrp) LOAD(bufA, g + 2);
            FMA(bufB, g + 1);
        }
        if (g < ngrp) FMA(bufA, g); // odd tail group
    }

    *(float2*)(out + (size_t)b * (T * D) + t * D + lane * 2) = acc;
}

extern "C" void kernel_launch(void* const* d_in, const int* in_sizes, int n_in,
                              void* d_out, int out_size, void* d_ws, size_t ws_size,
                              hipStream_t stream) {
    const float* tables  = (const float*)d_in[0];
    const int*   values  = (const int*)d_in[1];
    const int*   offsets = (const int*)d_in[2];
    const float* psw     = (const float*)d_in[3];
    float*       out     = (float*)d_out;

    for (int t = 0; t < T; ++t) {
        prestream_kernel<<<dim3(PRE_BLOCKS), dim3(256), 0, stream>>>(
            tables + (size_t)t * (V * D));
        gather_kernel<<<dim3(B / 4), dim3(256), 0, stream>>>(
            tables, values, offsets, psw, out, t);
    }
}